// Round 8
// baseline (760.027 us; speedup 1.0000x reference)
//
#include <hip/hip_runtime.h>

#define DIN 256
#define H   128
#define DOUT 64

#define EPI_RELU 0
#define EPI_BN   1
#define EPI_NONE 2

#define BKT_SHIFT 7                 // 128 nodes per bucket
#define BKT_NODES 128
#define BKT_CAP   4096              // slots per bucket (mean 2048, sigma ~45)
#define CSR_CAP   4608              // BKT_CAP + 128*3 align slack + 16 tail pad

typedef __attribute__((ext_vector_type(8))) short bf16x8;
typedef __attribute__((ext_vector_type(4))) float f32x4;

__device__ inline unsigned short f2bf(float f) {
  union { float f; unsigned u; } v; v.f = f;
  unsigned u = v.u;
  u += 0x7FFFu + ((u >> 16) & 1u);   // round-to-nearest-even
  return (unsigned short)(u >> 16);
}
__device__ inline float bf2f(unsigned u16) {
  union { unsigned u; float f; } v; v.u = u16 << 16;
  return v.f;
}
// pack two fp32 -> one u32 of 2x bf16, RNE via verified bit-twiddle
__device__ inline unsigned pk_bf16(float lo, float hi) {
  return (unsigned)f2bf(lo) | ((unsigned)f2bf(hi) << 16);
}

// async global->LDS DMA, 16B per lane; LDS dest = wave-uniform base + lane*16
__device__ inline void gload_lds16(const void* g, void* l) {
  __builtin_amdgcn_global_load_lds(
      (const __attribute__((address_space(1))) void*)g,
      (__attribute__((address_space(3))) void*)l, 16, 0, 0);
}

// ---------------- stage 1: bucket edges by dst>>7 ----------------
#define FILL_TPB 1024
#define FILL_EPT 16
#define FILL_EPB (FILL_TPB * FILL_EPT)

__global__ __launch_bounds__(FILL_TPB) void bucket_fill(
    const int* __restrict__ src, const int* __restrict__ dst,
    int* __restrict__ bcur, unsigned* __restrict__ bedges,
    int nbkt, int e) {
  __shared__ int hist[1024];        // >= nbkt (782)
  int tid = threadIdx.x;
  int base = blockIdx.x * FILL_EPB;
  for (int i = tid; i < nbkt; i += FILL_TPB) hist[i] = 0;
  __syncthreads();

  int es[FILL_EPT], ed[FILL_EPT];
#pragma unroll
  for (int j = 0; j < FILL_EPT; ++j) {
    int i = base + j * FILL_TPB + tid;
    if (i < e) {
      es[j] = src[i];
      ed[j] = dst[i];
      atomicAdd(&hist[ed[j] >> BKT_SHIFT], 1);
    } else {
      es[j] = -1; ed[j] = 0;
    }
  }
  __syncthreads();
  for (int b = tid; b < nbkt; b += FILL_TPB) {
    int cnt = hist[b];
    hist[b] = cnt ? atomicAdd(&bcur[b], cnt) : 0;
  }
  __syncthreads();
#pragma unroll
  for (int j = 0; j < FILL_EPT; ++j) {
    if (es[j] >= 0) {
      int b = ed[j] >> BKT_SHIFT;
      int p = atomicAdd(&hist[b], 1);
      if (p < BKT_CAP)
        bedges[(size_t)b * BKT_CAP + p] =
            (unsigned)es[j] | ((unsigned)(ed[j] & (BKT_NODES - 1)) << 17);
    }
  }
}

// ---------------- stage 2: in-LDS counting sort per bucket -> aligned CSR ----
__global__ __launch_bounds__(256) void bucket_sort(
    const int* __restrict__ bcur, const unsigned* __restrict__ bedges,
    int* __restrict__ csr, int2* __restrict__ rowdeg, int n) {
  __shared__ unsigned rec[BKT_CAP];
  __shared__ int srcs[CSR_CAP];
  __shared__ int hist[BKT_NODES];
  __shared__ int cursor[BKT_NODES];
  __shared__ int s_total;
  int tid = threadIdx.x;
  int b = blockIdx.x;
  int cnt = bcur[b];
  if (cnt > BKT_CAP) cnt = BKT_CAP;
  const unsigned* eb = bedges + (size_t)b * BKT_CAP;

  if (tid < BKT_NODES) hist[tid] = 0;
  __syncthreads();
  for (int i = tid; i < cnt; i += 256) {
    unsigned r = eb[i];
    rec[i] = r;
    atomicAdd(&hist[(r >> 17) & 127], 1);
  }
  __syncthreads();
  int myc = (tid < BKT_NODES) ? hist[tid] : 0;
  int myc4 = (myc + 3) & ~3;        // 16B-aligned row length
  if (tid < BKT_NODES) hist[tid] = myc4;
  __syncthreads();
#pragma unroll
  for (int off = 1; off < BKT_NODES; off <<= 1) {
    int v = 0;
    if (tid < BKT_NODES && tid >= off) v = hist[tid - off];
    __syncthreads();
    if (tid < BKT_NODES) hist[tid] += v;
    __syncthreads();
  }
  int start = 0;
  if (tid < BKT_NODES) {
    start = hist[tid] - myc4;
    cursor[tid] = start;
    int node = b * BKT_NODES + tid;
    if (node < n) rowdeg[node] = make_int2(b * CSR_CAP + start, myc);
    if (tid == BKT_NODES - 1) s_total = hist[tid];
  }
  __syncthreads();
  for (int i = tid; i < cnt; i += 256) {
    unsigned r = rec[i];
    int p = atomicAdd(&cursor[(r >> 17) & 127], 1);
    srcs[p] = (int)(r & 0x1FFFFu);
  }
  // zero alignment gaps (disjoint from scatter targets, no sync needed)
  if (tid < BKT_NODES) {
    for (int g = start + myc; g < start + myc4; ++g) srcs[g] = 0;
  }
  __syncthreads();
  int total = s_total;
  if (tid < 16 && total + tid < CSR_CAP) srcs[total + tid] = 0;  // tail pad
  __syncthreads();
  int tot16 = total + 16;
  if (tot16 > CSR_CAP) tot16 = CSR_CAP;
  for (int i = tid; i < tot16; i += 256)
    csr[(size_t)b * CSR_CAP + i] = srcs[i];
}

// ---------------- mean aggregation: 4 nodes/wave, uint4 gather --------------
__global__ __launch_bounds__(256) void agg_kernel(
    const unsigned* __restrict__ h, const int2* __restrict__ rowdeg,
    const int* __restrict__ csr, unsigned* __restrict__ mean, int n) {
  int wid = (blockIdx.x * 256 + threadIdx.x) >> 6;
  int lane = threadIdx.x & 63;
  int grp = lane >> 4;
  int c = lane & 15;
  int node = wid * 4 + grp;
  bool valid = node < n;
  if (!valid) node = 0;
  int2 rd = rowdeg[node];
  int beg = rd.x, d = rd.y;

  const uint4* hv = (const uint4*)h;
  float a[8];
#pragma unroll
  for (int k = 0; k < 8; ++k) a[k] = 0.f;

  for (int j0 = 0; j0 < d; j0 += 16) {
    int rem = d - j0;
    const int4* sp = (const int4*)(csr + beg + j0);   // 16B aligned
    int sv[16];
    *(int4*)&sv[0]  = sp[0];
    *(int4*)&sv[4]  = sp[1];
    *(int4*)&sv[8]  = sp[2];
    *(int4*)&sv[12] = sp[3];
#pragma unroll
    for (int jj = 0; jj < 16; ++jj) {
      float w = (jj < rem) ? 1.f : 0.f;
      uint4 v = hv[(unsigned)(sv[jj] * 16 + c)];
#pragma unroll
      for (int k = 0; k < 4; ++k) {
        unsigned u = ((const unsigned*)&v)[k];
        union { unsigned u; float f; } lo, hi;
        lo.u = u << 16;
        hi.u = u & 0xffff0000u;
        a[2 * k]     = fmaf(w, lo.f, a[2 * k]);
        a[2 * k + 1] = fmaf(w, hi.f, a[2 * k + 1]);
      }
    }
  }

  if (valid) {
    float invd = 1.f / (float)(d > 0 ? d : 1);
    uint4 o;
    o.x = pk_bf16(a[0] * invd, a[1] * invd);
    o.y = pk_bf16(a[2] * invd, a[3] * invd);
    o.z = pk_bf16(a[4] * invd, a[5] * invd);
    o.w = pk_bf16(a[6] * invd, a[7] * invd);
    ((uint4*)mean)[(unsigned)(node * 16 + c)] = o;
  }
}

// ---------------- weight preconvert: Wt[m][k] = bf16(W[k][m]) ----------------
__global__ __launch_bounds__(256) void prep_w(
    const float* __restrict__ w_in, const float* __restrict__ w_l1,
    const float* __restrict__ w_r1, const float* __restrict__ w_l2,
    const float* __restrict__ w_r2, const float* __restrict__ w_out,
    unsigned short* __restrict__ t_in, unsigned short* __restrict__ t_l1,
    unsigned short* __restrict__ t_r1, unsigned short* __restrict__ t_l2,
    unsigned short* __restrict__ t_r2, unsigned short* __restrict__ t_out) {
  int i = blockIdx.x * 256 + threadIdx.x;
  const float* s; unsigned short* d; int K, M, off;
  if (i < 32768)       { s = w_in;  d = t_in;  K = 256; M = 128; off = i; }
  else if (i < 49152)  { s = w_l1;  d = t_l1;  K = 128; M = 128; off = i - 32768; }
  else if (i < 65536)  { s = w_r1;  d = t_r1;  K = 128; M = 128; off = i - 49152; }
  else if (i < 81920)  { s = w_l2;  d = t_l2;  K = 128; M = 128; off = i - 65536; }
  else if (i < 98304)  { s = w_r2;  d = t_r2;  K = 128; M = 128; off = i - 81920; }
  else if (i < 106496) { s = w_out; d = t_out; K = 128; M = 64;  off = i - 98304; }
  else return;
  int m = off / K, k = off % K;
  d[off] = f2bf(s[(size_t)k * M + m]);
}

// ------------- bf16 MFMA GEMM v7: LDS-persistent B, barrier-free TLP loop ---
// 512-thread blocks (8 waves). All weights staged to LDS once per block with
// the v5-verified DMA + pre-swizzled-source code, ONE barrier, then each wave
// grid-strides over independent 16-row tiles reading A straight to registers
// (v4b-verified fragment math) and B from LDS per MFMA (v5-verified read).
// No sync in the loop -> A loads from different waves continuously overlap.
// Resource budget engineered against the v5/v6 failures:
//   __launch_bounds__(512,4) caps VGPR at 128 (est ~100: af 32 + acc 32 +
//   temps; epilogue constants re-read per tile, not hoisted); LDS 64KB ->
//   2 blocks/CU = 16 waves/CU, each ~8KB in flight => ~64KB/CU outstanding.
template <int K, int M, int NS, int EPI, bool AFP32, bool OUTF32>
__global__ __launch_bounds__(512, 4) void gemm_tlp(
    const void* __restrict__ A1, const void* __restrict__ A2,
    const unsigned short* __restrict__ W1, const unsigned short* __restrict__ W2,
    const float* __restrict__ bias, const float* __restrict__ gamma,
    const float* __restrict__ beta, void* __restrict__ Cv,
    int n, int ntiles, int nwaves) {
  constexpr int NT = M / 16;        // output col tiles per wave (full M)
  constexpr int KT = K / 32;        // k-steps
  constexpr int CH = K / 8;         // 16B chunks per weight row
  constexpr int RPI = 64 / CH;      // weight rows per DMA instruction
  constexpr int NI = (NS * M) / RPI;
  constexpr int WAVES = 8;
  __shared__ __align__(16) unsigned short Bs[NS * M * K];

  int tid = threadIdx.x, lane = tid & 63, wave = tid >> 6;
  int m16 = lane & 15, quad = lane >> 4;

  // ---- one-time weight stage (v5-verified DMA, pre-swizzled source) ----
#pragma unroll
  for (int g = 0; g < NI / WAVES; ++g) {
    int i = g * WAVES + wave;
    int r0 = i * RPI;                       // wave-uniform dest row
    int lr = r0 + lane / CH;                // per-lane weight row
    int sc = lane & (CH - 1);               // dest chunk
    int cs = (sc - lr) & (CH - 1);          // pre-swizzled source chunk
    const unsigned short* Ws = (NS == 2 && lr >= M) ? W2 : W1;
    int lrs = lr & (M - 1);
    gload_lds16(Ws + (size_t)lrs * K + cs * 8, &Bs[r0 * K]);
  }
  __syncthreads();                          // weights resident; only barrier

  const float inv_std = rsqrtf(1.f + 1e-5f);
  int wid = blockIdx.x * WAVES + wave;

  // ---- barrier-free grid-stride tile loop ----
  for (int t = wid; t < ntiles; t += nwaves) {
    int ra = t * 16 + m16;
    if (ra >= n) ra = n - 1;
    f32x4 acc[NT];
#pragma unroll
    for (int tt = 0; tt < NT; ++tt) acc[tt] = (f32x4){0.f, 0.f, 0.f, 0.f};

    if constexpr (!AFP32) {
      bf16x8 af[NS][KT];
#pragma unroll
      for (int s = 0; s < NS; ++s) {
        const unsigned short* Ap =
            (const unsigned short*)(s ? A2 : A1) + (size_t)ra * K;
#pragma unroll
        for (int kt = 0; kt < KT; ++kt)
          af[s][kt] = *(const bf16x8*)(Ap + (kt * 4 + quad) * 8);
      }
#pragma unroll
      for (int kt = 0; kt < KT; ++kt)
#pragma unroll
        for (int s = 0; s < NS; ++s)
#pragma unroll
          for (int tt = 0; tt < NT; ++tt) {
            int brow = s * M + tt * 16 + m16;
            bf16x8 b = *(const bf16x8*)
                &Bs[brow * K + (((kt * 4 + quad) + brow) & (CH - 1)) * 8];
            acc[tt] = __builtin_amdgcn_mfma_f32_16x16x32_bf16(
                af[s][kt], b, acc[tt], 0, 0, 0);
          }
    } else {
      float4 af[KT][2];
      const float* Ap = (const float*)A1 + (size_t)ra * K;
#pragma unroll
      for (int kt = 0; kt < KT; ++kt) {
        af[kt][0] = *(const float4*)(Ap + (kt * 4 + quad) * 8);
        af[kt][1] = *(const float4*)(Ap + (kt * 4 + quad) * 8 + 4);
      }
#pragma unroll
      for (int kt = 0; kt < KT; ++kt) {
        union { unsigned u[4]; bf16x8 v; } pk;
        pk.u[0] = pk_bf16(af[kt][0].x, af[kt][0].y);
        pk.u[1] = pk_bf16(af[kt][0].z, af[kt][0].w);
        pk.u[2] = pk_bf16(af[kt][1].x, af[kt][1].y);
        pk.u[3] = pk_bf16(af[kt][1].z, af[kt][1].w);
#pragma unroll
        for (int tt = 0; tt < NT; ++tt) {
          int brow = tt * 16 + m16;
          bf16x8 b = *(const bf16x8*)
              &Bs[brow * K + (((kt * 4 + quad) + brow) & (CH - 1)) * 8];
          acc[tt] = __builtin_amdgcn_mfma_f32_16x16x32_bf16(
              pk.v, b, acc[tt], 0, 0, 0);
        }
      }
    }

    // ---- epilogue: constants re-read per tile (keeps VGPR under 128) ----
#pragma unroll
    for (int tt = 0; tt < NT; ++tt) {
      int col = tt * 16 + m16;
      float bv = bias[col];
      float s2 = 1.f, b2 = 0.f;
      if constexpr (EPI == EPI_BN) {
        s2 = gamma[col] * inv_std;
        b2 = beta[col];
      }
#pragma unroll
      for (int r = 0; r < 4; ++r) {
        int row = t * 16 + quad * 4 + r;
        if (row < n) {
          float v = acc[tt][r] + bv;
          if constexpr (EPI == EPI_BN) v = fmaxf(v * s2 + b2, 0.f);
          else if constexpr (EPI == EPI_RELU) v = fmaxf(v, 0.f);
          if constexpr (OUTF32)
            ((float*)Cv)[(size_t)row * M + col] = v;
          else
            ((unsigned short*)Cv)[(size_t)row * M + col] = f2bf(v);
        }
      }
    }
  }
}

extern "C" void kernel_launch(void* const* d_in, const int* in_sizes, int n_in,
                              void* d_out, int out_size, void* d_ws, size_t ws_size,
                              hipStream_t stream) {
  const float* x     = (const float*)d_in[0];
  const int*   ei    = (const int*)d_in[1];
  const float* w_in  = (const float*)d_in[2];
  const float* b_in  = (const float*)d_in[3];
  const float* w_l1  = (const float*)d_in[4];
  const float* b_l1  = (const float*)d_in[5];
  const float* w_r1  = (const float*)d_in[6];
  const float* g1    = (const float*)d_in[7];
  const float* be1   = (const float*)d_in[8];
  const float* w_l2  = (const float*)d_in[9];
  const float* b_l2  = (const float*)d_in[10];
  const float* w_r2  = (const float*)d_in[11];
  const float* g2    = (const float*)d_in[12];
  const float* be2   = (const float*)d_in[13];
  const float* w_out = (const float*)d_in[14];
  const float* b_out = (const float*)d_in[15];
  float* out = (float*)d_out;

  int N = in_sizes[0] / DIN;
  int E = in_sizes[1] / 2;
  const int* src = ei;       // edge_index[0]
  const int* dst = ei + E;   // edge_index[1]
  int nbkt = (N + BKT_NODES - 1) / BKT_NODES;   // 782

  char* ws = (char*)d_ws;
  size_t off = 0;
  auto alloc = [&](size_t bytes) -> char* {
    char* p = ws + off;
    off += (bytes + 255) & ~(size_t)255;
    return p;
  };
  unsigned short* buf0 = (unsigned short*)alloc((size_t)N * H * 2);  // h0 -> mean2
  unsigned short* buf1 = (unsigned short*)alloc((size_t)N * H * 2);  // mean1 -> h2
  unsigned short* buf2 = (unsigned short*)alloc((size_t)N * H * 2);  // h1
  int* bcur        = (int*)alloc((size_t)nbkt * 4);
  unsigned* bedges = (unsigned*)alloc((size_t)nbkt * BKT_CAP * 4);
  int* csr         = (int*)alloc((size_t)nbkt * CSR_CAP * 4);
  int2* rowdeg     = (int2*)alloc((size_t)N * 8);
  unsigned short* t_in  = (unsigned short*)alloc(32768 * 2);
  unsigned short* t_l1  = (unsigned short*)alloc(16384 * 2);
  unsigned short* t_r1  = (unsigned short*)alloc(16384 * 2);
  unsigned short* t_l2  = (unsigned short*)alloc(16384 * 2);
  unsigned short* t_r2  = (unsigned short*)alloc(16384 * 2);
  unsigned short* t_out = (unsigned short*)alloc(8192 * 2);
  (void)ws_size;

  // ---- CSR build: bucket -> in-LDS counting sort (16B-aligned rows) ----
  hipMemsetAsync(bcur, 0, (size_t)nbkt * 4, stream);
  bucket_fill<<<(E + FILL_EPB - 1) / FILL_EPB, FILL_TPB, 0, stream>>>(
      src, dst, bcur, bedges, nbkt, E);
  bucket_sort<<<nbkt, 256, 0, stream>>>(bcur, bedges, csr, rowdeg, N);
  prep_w<<<(106496 + 255) / 256, 256, 0, stream>>>(
      w_in, w_l1, w_r1, w_l2, w_r2, w_out, t_in, t_l1, t_r1, t_l2, t_r2, t_out);

  int ntiles = (N + 15) / 16;          // 6250 16-row tiles
  int ablocks = (N + 15) / 16;         // agg: 4 nodes/wave, 4 waves/block
  const int GB = 512;                  // 512 blocks x 8 waves = 4096 waves
  const int NW = GB * 8;

  // h0 = relu(x @ w_in + b_in)       [fp32 A, K=256]
  gemm_tlp<256, 128, 1, EPI_RELU, true, false><<<GB, 512, 0, stream>>>(
      x, nullptr, t_in, nullptr, b_in, nullptr, nullptr, buf0, N, ntiles, NW);
  // mean1
  agg_kernel<<<ablocks, 256, 0, stream>>>((const unsigned*)buf0, rowdeg,
                                          csr, (unsigned*)buf1, N);
  // h1 = relu(bn(mean1@w_l1 + h0@w_r1 + b_l1))
  gemm_tlp<128, 128, 2, EPI_BN, false, false><<<GB, 512, 0, stream>>>(
      buf1, buf0, t_l1, t_r1, b_l1, g1, be1, buf2, N, ntiles, NW);
  // mean2
  agg_kernel<<<ablocks, 256, 0, stream>>>((const unsigned*)buf2, rowdeg,
                                          csr, (unsigned*)buf0, N);
  // h2 = relu(bn(mean2@w_l2 + h1@w_r2 + b_l2))
  gemm_tlp<128, 128, 2, EPI_BN, false, false><<<GB, 512, 0, stream>>>(
      buf0, buf2, t_l2, t_r2, b_l2, g2, be2, buf1, N, ntiles, NW);
  // out = h2 @ w_out + b_out         [fp32 out]
  gemm_tlp<128, 64, 1, EPI_NONE, false, true><<<GB, 512, 0, stream>>>(
      buf1, nullptr, t_out, nullptr, b_out, nullptr, nullptr, out, N, ntiles, NW);
}

// Round 9
// 436.482 us; speedup vs baseline: 1.7413x; 1.7413x over previous
//
#include <hip/hip_runtime.h>

#define DIN 256
#define H   128
#define DOUT 64

#define EPI_RELU 0
#define EPI_BN   1
#define EPI_NONE 2

#define BKT_SHIFT 7                 // 128 nodes per bucket
#define BKT_NODES 128
#define BKT_CAP   4096              // slots per bucket (mean 2048, sigma ~45)
#define CSR_CAP   4608              // BKT_CAP + 128*3 align slack + 16 tail pad

typedef __attribute__((ext_vector_type(8))) short bf16x8;
typedef __attribute__((ext_vector_type(4))) float f32x4;

__device__ inline unsigned short f2bf(float f) {
  union { float f; unsigned u; } v; v.f = f;
  unsigned u = v.u;
  u += 0x7FFFu + ((u >> 16) & 1u);   // round-to-nearest-even
  return (unsigned short)(u >> 16);
}
__device__ inline float bf2f(unsigned u16) {
  union { unsigned u; float f; } v; v.u = u16 << 16;
  return v.f;
}
// pack two fp32 -> one u32 of 2x bf16, RNE via verified bit-twiddle
__device__ inline unsigned pk_bf16(float lo, float hi) {
  return (unsigned)f2bf(lo) | ((unsigned)f2bf(hi) << 16);
}

// async global->LDS DMA, 16B per lane; LDS dest = wave-uniform base + lane*16
__device__ inline void gload_lds16(const void* g, void* l) {
  __builtin_amdgcn_global_load_lds(
      (const __attribute__((address_space(1))) void*)g,
      (__attribute__((address_space(3))) void*)l, 16, 0, 0);
}

// ---------------- stage 1: bucket edges by dst>>7 ----------------
#define FILL_TPB 1024
#define FILL_EPT 16
#define FILL_EPB (FILL_TPB * FILL_EPT)

__global__ __launch_bounds__(FILL_TPB) void bucket_fill(
    const int* __restrict__ src, const int* __restrict__ dst,
    int* __restrict__ bcur, unsigned* __restrict__ bedges,
    int nbkt, int e) {
  __shared__ int hist[1024];        // >= nbkt (782)
  int tid = threadIdx.x;
  int base = blockIdx.x * FILL_EPB;
  for (int i = tid; i < nbkt; i += FILL_TPB) hist[i] = 0;
  __syncthreads();

  int es[FILL_EPT], ed[FILL_EPT];
#pragma unroll
  for (int j = 0; j < FILL_EPT; ++j) {
    int i = base + j * FILL_TPB + tid;
    if (i < e) {
      es[j] = src[i];
      ed[j] = dst[i];
      atomicAdd(&hist[ed[j] >> BKT_SHIFT], 1);
    } else {
      es[j] = -1; ed[j] = 0;
    }
  }
  __syncthreads();
  for (int b = tid; b < nbkt; b += FILL_TPB) {
    int cnt = hist[b];
    hist[b] = cnt ? atomicAdd(&bcur[b], cnt) : 0;
  }
  __syncthreads();
#pragma unroll
  for (int j = 0; j < FILL_EPT; ++j) {
    if (es[j] >= 0) {
      int b = ed[j] >> BKT_SHIFT;
      int p = atomicAdd(&hist[b], 1);
      if (p < BKT_CAP)
        bedges[(size_t)b * BKT_CAP + p] =
            (unsigned)es[j] | ((unsigned)(ed[j] & (BKT_NODES - 1)) << 17);
    }
  }
}

// ---------------- stage 2: in-LDS counting sort per bucket -> aligned CSR ----
__global__ __launch_bounds__(256) void bucket_sort(
    const int* __restrict__ bcur, const unsigned* __restrict__ bedges,
    int* __restrict__ csr, int2* __restrict__ rowdeg, int n) {
  __shared__ unsigned rec[BKT_CAP];
  __shared__ int srcs[CSR_CAP];
  __shared__ int hist[BKT_NODES];
  __shared__ int cursor[BKT_NODES];
  __shared__ int s_total;
  int tid = threadIdx.x;
  int b = blockIdx.x;
  int cnt = bcur[b];
  if (cnt > BKT_CAP) cnt = BKT_CAP;
  const unsigned* eb = bedges + (size_t)b * BKT_CAP;

  if (tid < BKT_NODES) hist[tid] = 0;
  __syncthreads();
  for (int i = tid; i < cnt; i += 256) {
    unsigned r = eb[i];
    rec[i] = r;
    atomicAdd(&hist[(r >> 17) & 127], 1);
  }
  __syncthreads();
  int myc = (tid < BKT_NODES) ? hist[tid] : 0;
  int myc4 = (myc + 3) & ~3;        // 16B-aligned row length
  if (tid < BKT_NODES) hist[tid] = myc4;
  __syncthreads();
#pragma unroll
  for (int off = 1; off < BKT_NODES; off <<= 1) {
    int v = 0;
    if (tid < BKT_NODES && tid >= off) v = hist[tid - off];
    __syncthreads();
    if (tid < BKT_NODES) hist[tid] += v;
    __syncthreads();
  }
  int start = 0;
  if (tid < BKT_NODES) {
    start = hist[tid] - myc4;
    cursor[tid] = start;
    int node = b * BKT_NODES + tid;
    if (node < n) rowdeg[node] = make_int2(b * CSR_CAP + start, myc);
    if (tid == BKT_NODES - 1) s_total = hist[tid];
  }
  __syncthreads();
  for (int i = tid; i < cnt; i += 256) {
    unsigned r = rec[i];
    int p = atomicAdd(&cursor[(r >> 17) & 127], 1);
    srcs[p] = (int)(r & 0x1FFFFu);
  }
  // zero alignment gaps (disjoint from scatter targets, no sync needed)
  if (tid < BKT_NODES) {
    for (int g = start + myc; g < start + myc4; ++g) srcs[g] = 0;
  }
  __syncthreads();
  int total = s_total;
  if (tid < 16 && total + tid < CSR_CAP) srcs[total + tid] = 0;  // tail pad
  __syncthreads();
  int tot16 = total + 16;
  if (tot16 > CSR_CAP) tot16 = CSR_CAP;
  for (int i = tid; i < tot16; i += 256)
    csr[(size_t)b * CSR_CAP + i] = srcs[i];
}

// ---------------- mean aggregation: 4 nodes/wave, uint4 gather --------------
__global__ __launch_bounds__(256) void agg_kernel(
    const unsigned* __restrict__ h, const int2* __restrict__ rowdeg,
    const int* __restrict__ csr, unsigned* __restrict__ mean, int n) {
  int wid = (blockIdx.x * 256 + threadIdx.x) >> 6;
  int lane = threadIdx.x & 63;
  int grp = lane >> 4;
  int c = lane & 15;
  int node = wid * 4 + grp;
  bool valid = node < n;
  if (!valid) node = 0;
  int2 rd = rowdeg[node];
  int beg = rd.x, d = rd.y;

  const uint4* hv = (const uint4*)h;
  float a[8];
#pragma unroll
  for (int k = 0; k < 8; ++k) a[k] = 0.f;

  for (int j0 = 0; j0 < d; j0 += 16) {
    int rem = d - j0;
    const int4* sp = (const int4*)(csr + beg + j0);   // 16B aligned
    int sv[16];
    *(int4*)&sv[0]  = sp[0];
    *(int4*)&sv[4]  = sp[1];
    *(int4*)&sv[8]  = sp[2];
    *(int4*)&sv[12] = sp[3];
#pragma unroll
    for (int jj = 0; jj < 16; ++jj) {
      float w = (jj < rem) ? 1.f : 0.f;
      uint4 v = hv[(unsigned)(sv[jj] * 16 + c)];
#pragma unroll
      for (int k = 0; k < 4; ++k) {
        unsigned u = ((const unsigned*)&v)[k];
        union { unsigned u; float f; } lo, hi;
        lo.u = u << 16;
        hi.u = u & 0xffff0000u;
        a[2 * k]     = fmaf(w, lo.f, a[2 * k]);
        a[2 * k + 1] = fmaf(w, hi.f, a[2 * k + 1]);
      }
    }
  }

  if (valid) {
    float invd = 1.f / (float)(d > 0 ? d : 1);
    uint4 o;
    o.x = pk_bf16(a[0] * invd, a[1] * invd);
    o.y = pk_bf16(a[2] * invd, a[3] * invd);
    o.z = pk_bf16(a[4] * invd, a[5] * invd);
    o.w = pk_bf16(a[6] * invd, a[7] * invd);
    ((uint4*)mean)[(unsigned)(node * 16 + c)] = o;
  }
}

// ---------------- weight preconvert: Wt[m][k] = bf16(W[k][m]) ----------------
__global__ __launch_bounds__(256) void prep_w(
    const float* __restrict__ w_in, const float* __restrict__ w_l1,
    const float* __restrict__ w_r1, const float* __restrict__ w_l2,
    const float* __restrict__ w_r2, const float* __restrict__ w_out,
    unsigned short* __restrict__ t_in, unsigned short* __restrict__ t_l1,
    unsigned short* __restrict__ t_r1, unsigned short* __restrict__ t_l2,
    unsigned short* __restrict__ t_r2, unsigned short* __restrict__ t_out) {
  int i = blockIdx.x * 256 + threadIdx.x;
  const float* s; unsigned short* d; int K, M, off;
  if (i < 32768)       { s = w_in;  d = t_in;  K = 256; M = 128; off = i; }
  else if (i < 49152)  { s = w_l1;  d = t_l1;  K = 128; M = 128; off = i - 32768; }
  else if (i < 65536)  { s = w_r1;  d = t_r1;  K = 128; M = 128; off = i - 49152; }
  else if (i < 81920)  { s = w_l2;  d = t_l2;  K = 128; M = 128; off = i - 65536; }
  else if (i < 98304)  { s = w_r2;  d = t_r2;  K = 128; M = 128; off = i - 81920; }
  else if (i < 106496) { s = w_out; d = t_out; K = 128; M = 64;  off = i - 98304; }
  else return;
  int m = off / K, k = off % K;
  d[off] = f2bf(s[(size_t)k * M + m]);
}

// ---------------- bf16 MFMA GEMM v8: v4b base, optional merged phases -------
// Base structure = verified v4b (round 4, 420us): 64 rows/block, 4 waves,
// A direct-to-regs, B via global_load_lds with pre-swizzled source.
// MERGE=true (gemm2/3 only): stage BOTH phases' B tiles into a doubled LDS
// buffer and BOTH phases' A-frags into regs, then ONE barrier, then all 64
// MFMAs back-to-back. Removes v4b's per-phase vmcnt(0)+barrier convoy (the
// round-4 counters: MfmaUtil 3.7%, VALUBusy 9%, HBM 15% -- all pipes idle)
// while staying fully straight-line/unrolled (the only shape hipcc's
// allocator has handled cleanly: v4b=60 VGPR/no scratch vs v5/v6/v7 spills).
// MERGE=false: byte-identical v4b behavior (gemm1 fp32-A would need ~140
// VGPR merged -> spill risk; gemm4 is single-phase anyway).
template <int NPH, int KOFF2, int AKA, int AKW, int M, int EPI, bool AFP32,
          bool OUTF32, bool MERGE>
__global__ __launch_bounds__(256) void gemm_mfma(
    const void* __restrict__ A1, const void* __restrict__ A2,
    const unsigned short* __restrict__ W1, const unsigned short* __restrict__ W2,
    const float* __restrict__ bias, const float* __restrict__ gamma,
    const float* __restrict__ beta, void* __restrict__ Cv, int n) {
  constexpr int NT = M / 16;
  constexpr int NB = MERGE ? 2 : 1;
  __shared__ __align__(16) unsigned short Bs[NB * M * 128];  // 32/64 KB

  int tid = threadIdx.x, lane = tid & 63, wave = tid >> 6;
  int m16 = lane & 15, quad = lane >> 4;
  int row0 = blockIdx.x * 64;
  int sr = lane >> 4;          // B-stage: row-in-group 0..3
  int sc = lane & 15;          // B-stage: dest 16B chunk 0..15

  int arow = row0 + wave * 16 + m16;
  if (arow >= n) arow = n - 1;

  f32x4 acc[NT];
#pragma unroll
  for (int t = 0; t < NT; ++t) acc[t] = (f32x4){0.f, 0.f, 0.f, 0.f};

  if constexpr (MERGE) {
    // ---- stage B for BOTH phases (16 DMA issues, no intervening barrier) --
#pragma unroll
    for (int ph = 0; ph < 2; ++ph) {
      const unsigned short* W = ph ? W2 : W1;
#pragma unroll
      for (int g = 0; g < M / 16; ++g) {
        int br = wave * (M / 4) + g * 4 + sr;
        int cs = (sc - br) & 15;                  // pre-swizzled source chunk
        gload_lds16(W + (size_t)br * AKW + cs * 8,
                    &Bs[(ph * M + wave * (M / 4) + g * 4) * 128]);
      }
    }
    // ---- A fragments for BOTH phases straight to registers ----
    bf16x8 afrag[2][4];
#pragma unroll
    for (int ph = 0; ph < 2; ++ph) {
      const unsigned short* Ab =
          (const unsigned short*)(ph ? A2 : A1) + (size_t)arow * AKA;
#pragma unroll
      for (int kt = 0; kt < 4; ++kt)
        afrag[ph][kt] = *(const bf16x8*)(Ab + (kt * 4 + quad) * 8);
    }
    __syncthreads();   // the ONLY barrier: drains all DMA + A loads

    // ---- 64 MFMAs back-to-back, LDS + regs only ----
#pragma unroll
    for (int ph = 0; ph < 2; ++ph)
#pragma unroll
      for (int kt = 0; kt < 4; ++kt) {
        int ch = kt * 4 + quad;
#pragma unroll
        for (int t = 0; t < NT; ++t) {
          int brow = t * 16 + m16;
          bf16x8 b = *(const bf16x8*)
              &Bs[(ph * M + brow) * 128 + ((ch + brow) & 15) * 8];
          acc[t] = __builtin_amdgcn_mfma_f32_16x16x32_bf16(
              afrag[ph][kt], b, acc[t], 0, 0, 0);
        }
      }
  } else {
    // ---- byte-identical v4b path ----
#pragma unroll
    for (int ph = 0; ph < NPH; ++ph) {
      const void* A_ = ph ? A2 : A1;
      const unsigned short* W = ph ? W2 : W1;
      const int koff = ph ? KOFF2 : 0;
      if (ph) __syncthreads();   // waves done reading previous B tile

#pragma unroll
      for (int g = 0; g < M / 16; ++g) {
        int br = wave * (M / 4) + g * 4 + sr;
        int cs = (sc - br) & 15;                  // pre-swizzled source chunk
        gload_lds16(W + (size_t)br * AKW + koff + cs * 8,
                    &Bs[(wave * (M / 4) + g * 4) * 128]);
      }

      bf16x8 afrag[4];
      if constexpr (!AFP32) {
        const unsigned short* Ab =
            (const unsigned short*)A_ + (size_t)arow * AKA + koff;
#pragma unroll
        for (int kt = 0; kt < 4; ++kt)
          afrag[kt] = *(const bf16x8*)(Ab + (kt * 4 + quad) * 8);
      } else {
        const float* Af = (const float*)A_ + (size_t)arow * AKA + koff;
#pragma unroll
        for (int kt = 0; kt < 4; ++kt) {
          float4 v0 = *(const float4*)(Af + (kt * 4 + quad) * 8);
          float4 v1 = *(const float4*)(Af + (kt * 4 + quad) * 8 + 4);
          union { unsigned u[4]; bf16x8 v; } pk;
          pk.u[0] = pk_bf16(v0.x, v0.y);
          pk.u[1] = pk_bf16(v0.z, v0.w);
          pk.u[2] = pk_bf16(v1.x, v1.y);
          pk.u[3] = pk_bf16(v1.z, v1.w);
          afrag[kt] = pk.v;
        }
      }
      __syncthreads();   // drains B DMA (vmcnt) + A loads

#pragma unroll
      for (int kt = 0; kt < 4; ++kt) {
        int ch = kt * 4 + quad;
#pragma unroll
        for (int t = 0; t < NT; ++t) {
          int brow = t * 16 + m16;
          bf16x8 b = *(const bf16x8*)&Bs[brow * 128 + ((ch + brow) & 15) * 8];
          acc[t] = __builtin_amdgcn_mfma_f32_16x16x32_bf16(
              afrag[kt], b, acc[t], 0, 0, 0);
        }
      }
    }
  }

  const float inv_std = rsqrtf(1.f + 1e-5f);
#pragma unroll
  for (int t = 0; t < NT; ++t) {
    int col = t * 16 + m16;
    float bv = bias[col];
    float sc2 = 1.f, bt2 = 0.f;
    if constexpr (EPI == EPI_BN) {
      sc2 = gamma[col] * inv_std;
      bt2 = beta[col];
    }
#pragma unroll
    for (int r = 0; r < 4; ++r) {
      int row = row0 + wave * 16 + quad * 4 + r;
      if (row < n) {
        float v = acc[t][r] + bv;
        if constexpr (EPI == EPI_BN) v = fmaxf(v * sc2 + bt2, 0.f);
        else if constexpr (EPI == EPI_RELU) v = fmaxf(v, 0.f);
        if constexpr (OUTF32)
          ((float*)Cv)[(size_t)row * M + col] = v;
        else
          ((unsigned short*)Cv)[(size_t)row * M + col] = f2bf(v);
      }
    }
  }
}

extern "C" void kernel_launch(void* const* d_in, const int* in_sizes, int n_in,
                              void* d_out, int out_size, void* d_ws, size_t ws_size,
                              hipStream_t stream) {
  const float* x     = (const float*)d_in[0];
  const int*   ei    = (const int*)d_in[1];
  const float* w_in  = (const float*)d_in[2];
  const float* b_in  = (const float*)d_in[3];
  const float* w_l1  = (const float*)d_in[4];
  const float* b_l1  = (const float*)d_in[5];
  const float* w_r1  = (const float*)d_in[6];
  const float* g1    = (const float*)d_in[7];
  const float* be1   = (const float*)d_in[8];
  const float* w_l2  = (const float*)d_in[9];
  const float* b_l2  = (const float*)d_in[10];
  const float* w_r2  = (const float*)d_in[11];
  const float* g2    = (const float*)d_in[12];
  const float* be2   = (const float*)d_in[13];
  const float* w_out = (const float*)d_in[14];
  const float* b_out = (const float*)d_in[15];
  float* out = (float*)d_out;

  int N = in_sizes[0] / DIN;
  int E = in_sizes[1] / 2;
  const int* src = ei;       // edge_index[0]
  const int* dst = ei + E;   // edge_index[1]
  int nbkt = (N + BKT_NODES - 1) / BKT_NODES;   // 782

  char* ws = (char*)d_ws;
  size_t off = 0;
  auto alloc = [&](size_t bytes) -> char* {
    char* p = ws + off;
    off += (bytes + 255) & ~(size_t)255;
    return p;
  };
  unsigned short* buf0 = (unsigned short*)alloc((size_t)N * H * 2);  // h0 -> mean2
  unsigned short* buf1 = (unsigned short*)alloc((size_t)N * H * 2);  // mean1 -> h2
  unsigned short* buf2 = (unsigned short*)alloc((size_t)N * H * 2);  // h1
  int* bcur        = (int*)alloc((size_t)nbkt * 4);
  unsigned* bedges = (unsigned*)alloc((size_t)nbkt * BKT_CAP * 4);
  int* csr         = (int*)alloc((size_t)nbkt * CSR_CAP * 4);
  int2* rowdeg     = (int2*)alloc((size_t)N * 8);
  unsigned short* t_in  = (unsigned short*)alloc(32768 * 2);
  unsigned short* t_l1  = (unsigned short*)alloc(16384 * 2);
  unsigned short* t_r1  = (unsigned short*)alloc(16384 * 2);
  unsigned short* t_l2  = (unsigned short*)alloc(16384 * 2);
  unsigned short* t_r2  = (unsigned short*)alloc(16384 * 2);
  unsigned short* t_out = (unsigned short*)alloc(8192 * 2);
  (void)ws_size;

  // ---- CSR build: bucket -> in-LDS counting sort (16B-aligned rows) ----
  hipMemsetAsync(bcur, 0, (size_t)nbkt * 4, stream);
  bucket_fill<<<(E + FILL_EPB - 1) / FILL_EPB, FILL_TPB, 0, stream>>>(
      src, dst, bcur, bedges, nbkt, E);
  bucket_sort<<<nbkt, 256, 0, stream>>>(bcur, bedges, csr, rowdeg, N);
  prep_w<<<(106496 + 255) / 256, 256, 0, stream>>>(
      w_in, w_l1, w_r1, w_l2, w_r2, w_out, t_in, t_l1, t_r1, t_l2, t_r2, t_out);

  int gblocks = (N + 63) / 64;   // 1563
  int ablocks = (N + 15) / 16;   // 6250 (4 nodes per wave, 4 waves per block)

  // h0 = relu(x @ w_in + b_in)       [fp32 A, K=256 via 2 phases; v4b path]
  gemm_mfma<2, 128, 256, 256, 128, EPI_RELU, true, false, false>
      <<<gblocks, 256, 0, stream>>>(
      x, x, t_in, t_in, b_in, nullptr, nullptr, buf0, N);
  // mean1
  agg_kernel<<<ablocks, 256, 0, stream>>>((const unsigned*)buf0, rowdeg,
                                          csr, (unsigned*)buf1, N);
  // h1 = relu(bn(mean1@w_l1 + h0@w_r1 + b_l1))   [MERGED single-barrier]
  gemm_mfma<2, 0, 128, 128, 128, EPI_BN, false, false, true>
      <<<gblocks, 256, 0, stream>>>(
      buf1, buf0, t_l1, t_r1, b_l1, g1, be1, buf2, N);
  // mean2
  agg_kernel<<<ablocks, 256, 0, stream>>>((const unsigned*)buf2, rowdeg,
                                          csr, (unsigned*)buf0, N);
  // h2 = relu(bn(mean2@w_l2 + h1@w_r2 + b_l2))   [MERGED single-barrier]
  gemm_mfma<2, 0, 128, 128, 128, EPI_BN, false, false, true>
      <<<gblocks, 256, 0, stream>>>(
      buf0, buf2, t_l2, t_r2, b_l2, g2, be2, buf1, N);
  // out = h2 @ w_out + b_out         [single phase; v4b path]
  gemm_mfma<1, 0, 128, 128, 64, EPI_NONE, false, true, false>
      <<<gblocks, 256, 0, stream>>>(
      buf1, buf1, t_out, t_out, b_out, nullptr, nullptr, out, N);
}

// Round 10
// 429.375 us; speedup vs baseline: 1.7701x; 1.0166x over previous
//
#include <hip/hip_runtime.h>

#define DIN 256
#define H   128
#define DOUT 64

#define EPI_RELU 0
#define EPI_BN   1
#define EPI_NONE 2

#define BKT_SHIFT 7                 // 128 nodes per bucket
#define BKT_NODES 128
#define BKT_CAP   4096              // slots per bucket (mean 2048, sigma ~45)
#define CSR_CAP   4608              // BKT_CAP + 128*3 align slack + 16 tail pad

typedef __attribute__((ext_vector_type(8))) short bf16x8;
typedef __attribute__((ext_vector_type(4))) float f32x4;

__device__ inline unsigned short f2bf(float f) {
  union { float f; unsigned u; } v; v.f = f;
  unsigned u = v.u;
  u += 0x7FFFu + ((u >> 16) & 1u);   // round-to-nearest-even
  return (unsigned short)(u >> 16);
}
__device__ inline float bf2f(unsigned u16) {
  union { unsigned u; float f; } v; v.u = u16 << 16;
  return v.f;
}
// pack two fp32 -> one u32 of 2x bf16, RNE via verified bit-twiddle
__device__ inline unsigned pk_bf16(float lo, float hi) {
  return (unsigned)f2bf(lo) | ((unsigned)f2bf(hi) << 16);
}

// async global->LDS DMA, 16B per lane; LDS dest = wave-uniform base + lane*16
__device__ inline void gload_lds16(const void* g, void* l) {
  __builtin_amdgcn_global_load_lds(
      (const __attribute__((address_space(1))) void*)g,
      (__attribute__((address_space(3))) void*)l, 16, 0, 0);
}

// ---------------- stage 1: bucket edges by dst>>7 ----------------
#define FILL_TPB 1024
#define FILL_EPT 16
#define FILL_EPB (FILL_TPB * FILL_EPT)

__global__ __launch_bounds__(FILL_TPB) void bucket_fill(
    const int* __restrict__ src, const int* __restrict__ dst,
    int* __restrict__ bcur, unsigned* __restrict__ bedges,
    int nbkt, int e) {
  __shared__ int hist[1024];        // >= nbkt (782)
  int tid = threadIdx.x;
  int base = blockIdx.x * FILL_EPB;
  for (int i = tid; i < nbkt; i += FILL_TPB) hist[i] = 0;
  __syncthreads();

  int es[FILL_EPT], ed[FILL_EPT];
#pragma unroll
  for (int j = 0; j < FILL_EPT; ++j) {
    int i = base + j * FILL_TPB + tid;
    if (i < e) {
      es[j] = src[i];
      ed[j] = dst[i];
      atomicAdd(&hist[ed[j] >> BKT_SHIFT], 1);
    } else {
      es[j] = -1; ed[j] = 0;
    }
  }
  __syncthreads();
  for (int b = tid; b < nbkt; b += FILL_TPB) {
    int cnt = hist[b];
    hist[b] = cnt ? atomicAdd(&bcur[b], cnt) : 0;
  }
  __syncthreads();
#pragma unroll
  for (int j = 0; j < FILL_EPT; ++j) {
    if (es[j] >= 0) {
      int b = ed[j] >> BKT_SHIFT;
      int p = atomicAdd(&hist[b], 1);
      if (p < BKT_CAP)
        bedges[(size_t)b * BKT_CAP + p] =
            (unsigned)es[j] | ((unsigned)(ed[j] & (BKT_NODES - 1)) << 17);
    }
  }
}

// ---------------- stage 2: in-LDS counting sort per bucket -> aligned CSR ----
__global__ __launch_bounds__(256) void bucket_sort(
    const int* __restrict__ bcur, const unsigned* __restrict__ bedges,
    int* __restrict__ csr, int2* __restrict__ rowdeg, int n) {
  __shared__ unsigned rec[BKT_CAP];
  __shared__ int srcs[CSR_CAP];
  __shared__ int hist[BKT_NODES];
  __shared__ int cursor[BKT_NODES];
  __shared__ int s_total;
  int tid = threadIdx.x;
  int b = blockIdx.x;
  int cnt = bcur[b];
  if (cnt > BKT_CAP) cnt = BKT_CAP;
  const unsigned* eb = bedges + (size_t)b * BKT_CAP;

  if (tid < BKT_NODES) hist[tid] = 0;
  __syncthreads();
  for (int i = tid; i < cnt; i += 256) {
    unsigned r = eb[i];
    rec[i] = r;
    atomicAdd(&hist[(r >> 17) & 127], 1);
  }
  __syncthreads();
  int myc = (tid < BKT_NODES) ? hist[tid] : 0;
  int myc4 = (myc + 3) & ~3;        // 16B-aligned row length
  if (tid < BKT_NODES) hist[tid] = myc4;
  __syncthreads();
#pragma unroll
  for (int off = 1; off < BKT_NODES; off <<= 1) {
    int v = 0;
    if (tid < BKT_NODES && tid >= off) v = hist[tid - off];
    __syncthreads();
    if (tid < BKT_NODES) hist[tid] += v;
    __syncthreads();
  }
  int start = 0;
  if (tid < BKT_NODES) {
    start = hist[tid] - myc4;
    cursor[tid] = start;
    int node = b * BKT_NODES + tid;
    if (node < n) rowdeg[node] = make_int2(b * CSR_CAP + start, myc);
    if (tid == BKT_NODES - 1) s_total = hist[tid];
  }
  __syncthreads();
  for (int i = tid; i < cnt; i += 256) {
    unsigned r = rec[i];
    int p = atomicAdd(&cursor[(r >> 17) & 127], 1);
    srcs[p] = (int)(r & 0x1FFFFu);
  }
  // zero alignment gaps (disjoint from scatter targets, no sync needed)
  if (tid < BKT_NODES) {
    for (int g = start + myc; g < start + myc4; ++g) srcs[g] = 0;
  }
  __syncthreads();
  int total = s_total;
  if (tid < 16 && total + tid < CSR_CAP) srcs[total + tid] = 0;  // tail pad
  __syncthreads();
  int tot16 = total + 16;
  if (tot16 > CSR_CAP) tot16 = CSR_CAP;
  for (int i = tid; i < tot16; i += 256)
    csr[(size_t)b * CSR_CAP + i] = srcs[i];
}

// ---------------- mean aggregation: 4 nodes/wave, uint4 gather --------------
__global__ __launch_bounds__(256) void agg_kernel(
    const unsigned* __restrict__ h, const int2* __restrict__ rowdeg,
    const int* __restrict__ csr, unsigned* __restrict__ mean, int n) {
  int wid = (blockIdx.x * 256 + threadIdx.x) >> 6;
  int lane = threadIdx.x & 63;
  int grp = lane >> 4;
  int c = lane & 15;
  int node = wid * 4 + grp;
  bool valid = node < n;
  if (!valid) node = 0;
  int2 rd = rowdeg[node];
  int beg = rd.x, d = rd.y;

  const uint4* hv = (const uint4*)h;
  float a[8];
#pragma unroll
  for (int k = 0; k < 8; ++k) a[k] = 0.f;

  for (int j0 = 0; j0 < d; j0 += 16) {
    int rem = d - j0;
    const int4* sp = (const int4*)(csr + beg + j0);   // 16B aligned
    int sv[16];
    *(int4*)&sv[0]  = sp[0];
    *(int4*)&sv[4]  = sp[1];
    *(int4*)&sv[8]  = sp[2];
    *(int4*)&sv[12] = sp[3];
#pragma unroll
    for (int jj = 0; jj < 16; ++jj) {
      float w = (jj < rem) ? 1.f : 0.f;
      uint4 v = hv[(unsigned)(sv[jj] * 16 + c)];
#pragma unroll
      for (int k = 0; k < 4; ++k) {
        unsigned u = ((const unsigned*)&v)[k];
        union { unsigned u; float f; } lo, hi;
        lo.u = u << 16;
        hi.u = u & 0xffff0000u;
        a[2 * k]     = fmaf(w, lo.f, a[2 * k]);
        a[2 * k + 1] = fmaf(w, hi.f, a[2 * k + 1]);
      }
    }
  }

  if (valid) {
    float invd = 1.f / (float)(d > 0 ? d : 1);
    uint4 o;
    o.x = pk_bf16(a[0] * invd, a[1] * invd);
    o.y = pk_bf16(a[2] * invd, a[3] * invd);
    o.z = pk_bf16(a[4] * invd, a[5] * invd);
    o.w = pk_bf16(a[6] * invd, a[7] * invd);
    ((uint4*)mean)[(unsigned)(node * 16 + c)] = o;
  }
}

// ---------------- weight preconvert: Wt[m][k] = bf16(W[k][m]) ----------------
__global__ __launch_bounds__(256) void prep_w(
    const float* __restrict__ w_in, const float* __restrict__ w_l1,
    const float* __restrict__ w_r1, const float* __restrict__ w_l2,
    const float* __restrict__ w_r2, const float* __restrict__ w_out,
    unsigned short* __restrict__ t_in, unsigned short* __restrict__ t_l1,
    unsigned short* __restrict__ t_r1, unsigned short* __restrict__ t_l2,
    unsigned short* __restrict__ t_r2, unsigned short* __restrict__ t_out) {
  int i = blockIdx.x * 256 + threadIdx.x;
  const float* s; unsigned short* d; int K, M, off;
  if (i < 32768)       { s = w_in;  d = t_in;  K = 256; M = 128; off = i; }
  else if (i < 49152)  { s = w_l1;  d = t_l1;  K = 128; M = 128; off = i - 32768; }
  else if (i < 65536)  { s = w_r1;  d = t_r1;  K = 128; M = 128; off = i - 49152; }
  else if (i < 81920)  { s = w_l2;  d = t_l2;  K = 128; M = 128; off = i - 65536; }
  else if (i < 98304)  { s = w_r2;  d = t_r2;  K = 128; M = 128; off = i - 81920; }
  else if (i < 106496) { s = w_out; d = t_out; K = 128; M = 64;  off = i - 98304; }
  else return;
  int m = off / K, k = off % K;
  d[off] = f2bf(s[(size_t)k * M + m]);
}

// ---------------- bf16 MFMA GEMM v9: merged phases + 2 row-tiles/block ------
// Base = verified v4b. MERGE=true (gemm2/3): one block covers 128 rows as two
// 64-row tiles sharing one B-stage (both phases in 64KB LDS):
//   stage B (16 DMA) + load tile0 A-frags -> ONE barrier ->
//   issue tile1 A-frags (in flight during tile0 compute) ->
//   tile0: 64 MFMA + store -> tile1: 64 MFMA + store.
// Rationale (round-4 Little's law: 1.2TB/s = ~1.9KB in flight/CU, duty ~15%):
// tile1's 8KB rides out tile0's 512-cyc compute, B staging amortized 2x,
// 782 blocks = 3/CU sequential. Straight-line/unrolled throughout -- the only
// shape hipcc's allocator has handled cleanly (v5/v6/v7 all spilled loops).
// Peak live regs ~ a0(32)+a1(32)+acc(32)+temps < 128.
// MERGE=false: byte-identical v4b path (gemm1 fp32-A, gemm4).
template <int NPH, int KOFF2, int AKA, int AKW, int M, int EPI, bool AFP32,
          bool OUTF32, bool MERGE>
__global__ __launch_bounds__(256) void gemm_mfma(
    const void* __restrict__ A1, const void* __restrict__ A2,
    const unsigned short* __restrict__ W1, const unsigned short* __restrict__ W2,
    const float* __restrict__ bias, const float* __restrict__ gamma,
    const float* __restrict__ beta, void* __restrict__ Cv, int n) {
  constexpr int NT = M / 16;
  constexpr int NB = MERGE ? 2 : 1;
  __shared__ __align__(16) unsigned short Bs[NB * M * 128];  // 32/64 KB

  int tid = threadIdx.x, lane = tid & 63, wave = tid >> 6;
  int m16 = lane & 15, quad = lane >> 4;
  int row0 = blockIdx.x * (MERGE ? 128 : 64);
  int sr = lane >> 4;          // B-stage: row-in-group 0..3
  int sc = lane & 15;          // B-stage: dest 16B chunk 0..15

  const float inv_std = rsqrtf(1.f + 1e-5f);

  // epilogue+store for one 64-row tile (acc passed by ref, baseRow absolute)
  auto STORE = [&](f32x4 (&acc)[NT], int baseRow) {
#pragma unroll
    for (int t = 0; t < NT; ++t) {
      int col = t * 16 + m16;
      float bv = bias[col];
      float sc2 = 1.f, bt2 = 0.f;
      if constexpr (EPI == EPI_BN) {
        sc2 = gamma[col] * inv_std;
        bt2 = beta[col];
      }
#pragma unroll
      for (int r = 0; r < 4; ++r) {
        int row = baseRow + wave * 16 + quad * 4 + r;
        if (row < n) {
          float v = acc[t][r] + bv;
          if constexpr (EPI == EPI_BN) v = fmaxf(v * sc2 + bt2, 0.f);
          else if constexpr (EPI == EPI_RELU) v = fmaxf(v, 0.f);
          if constexpr (OUTF32)
            ((float*)Cv)[(size_t)row * M + col] = v;
          else
            ((unsigned short*)Cv)[(size_t)row * M + col] = f2bf(v);
        }
      }
    }
  };

  if constexpr (MERGE) {
    // ---- stage B for BOTH phases (16 DMA issues) ----
#pragma unroll
    for (int ph = 0; ph < 2; ++ph) {
      const unsigned short* W = ph ? W2 : W1;
#pragma unroll
      for (int g = 0; g < M / 16; ++g) {
        int br = wave * (M / 4) + g * 4 + sr;
        int cs = (sc - br) & 15;                  // pre-swizzled source chunk
        gload_lds16(W + (size_t)br * AKW + cs * 8,
                    &Bs[(ph * M + wave * (M / 4) + g * 4) * 128]);
      }
    }
    // ---- tile0 A fragments (both phases) ----
    int ar0 = row0 + wave * 16 + m16;      if (ar0 >= n) ar0 = n - 1;
    int ar1 = row0 + 64 + wave * 16 + m16; if (ar1 >= n) ar1 = n - 1;
    bf16x8 a0[2][4];
#pragma unroll
    for (int ph = 0; ph < 2; ++ph) {
      const unsigned short* Ab =
          (const unsigned short*)(ph ? A2 : A1) + (size_t)ar0 * AKA;
#pragma unroll
      for (int kt = 0; kt < 4; ++kt)
        a0[ph][kt] = *(const bf16x8*)(Ab + (kt * 4 + quad) * 8);
    }
    __syncthreads();   // drains B DMA + tile0 A loads

    // ---- tile1 A fragments: issued NOW, consumed after tile0 compute ----
    bf16x8 a1[2][4];
#pragma unroll
    for (int ph = 0; ph < 2; ++ph) {
      const unsigned short* Ab =
          (const unsigned short*)(ph ? A2 : A1) + (size_t)ar1 * AKA;
#pragma unroll
      for (int kt = 0; kt < 4; ++kt)
        a1[ph][kt] = *(const bf16x8*)(Ab + (kt * 4 + quad) * 8);
    }

    // ---- tile0: 64 MFMA + store (tile1 loads in flight) ----
    f32x4 acc[NT];
#pragma unroll
    for (int t = 0; t < NT; ++t) acc[t] = (f32x4){0.f, 0.f, 0.f, 0.f};
#pragma unroll
    for (int ph = 0; ph < 2; ++ph)
#pragma unroll
      for (int kt = 0; kt < 4; ++kt) {
        int ch = kt * 4 + quad;
#pragma unroll
        for (int t = 0; t < NT; ++t) {
          int brow = t * 16 + m16;
          bf16x8 b = *(const bf16x8*)
              &Bs[(ph * M + brow) * 128 + ((ch + brow) & 15) * 8];
          acc[t] = __builtin_amdgcn_mfma_f32_16x16x32_bf16(
              a0[ph][kt], b, acc[t], 0, 0, 0);
        }
      }
    STORE(acc, row0);

    // ---- tile1: 64 MFMA + store ----
#pragma unroll
    for (int t = 0; t < NT; ++t) acc[t] = (f32x4){0.f, 0.f, 0.f, 0.f};
#pragma unroll
    for (int ph = 0; ph < 2; ++ph)
#pragma unroll
      for (int kt = 0; kt < 4; ++kt) {
        int ch = kt * 4 + quad;
#pragma unroll
        for (int t = 0; t < NT; ++t) {
          int brow = t * 16 + m16;
          bf16x8 b = *(const bf16x8*)
              &Bs[(ph * M + brow) * 128 + ((ch + brow) & 15) * 8];
          acc[t] = __builtin_amdgcn_mfma_f32_16x16x32_bf16(
              a1[ph][kt], b, acc[t], 0, 0, 0);
        }
      }
    STORE(acc, row0 + 64);
  } else {
    // ---- byte-identical v4b path ----
    int arow = row0 + wave * 16 + m16;
    if (arow >= n) arow = n - 1;
    f32x4 acc[NT];
#pragma unroll
    for (int t = 0; t < NT; ++t) acc[t] = (f32x4){0.f, 0.f, 0.f, 0.f};

#pragma unroll
    for (int ph = 0; ph < NPH; ++ph) {
      const void* A_ = ph ? A2 : A1;
      const unsigned short* W = ph ? W2 : W1;
      const int koff = ph ? KOFF2 : 0;
      if (ph) __syncthreads();   // waves done reading previous B tile

#pragma unroll
      for (int g = 0; g < M / 16; ++g) {
        int br = wave * (M / 4) + g * 4 + sr;
        int cs = (sc - br) & 15;                  // pre-swizzled source chunk
        gload_lds16(W + (size_t)br * AKW + koff + cs * 8,
                    &Bs[(wave * (M / 4) + g * 4) * 128]);
      }

      bf16x8 afrag[4];
      if constexpr (!AFP32) {
        const unsigned short* Ab =
            (const unsigned short*)A_ + (size_t)arow * AKA + koff;
#pragma unroll
        for (int kt = 0; kt < 4; ++kt)
          afrag[kt] = *(const bf16x8*)(Ab + (kt * 4 + quad) * 8);
      } else {
        const float* Af = (const float*)A_ + (size_t)arow * AKA + koff;
#pragma unroll
        for (int kt = 0; kt < 4; ++kt) {
          float4 v0 = *(const float4*)(Af + (kt * 4 + quad) * 8);
          float4 v1 = *(const float4*)(Af + (kt * 4 + quad) * 8 + 4);
          union { unsigned u[4]; bf16x8 v; } pk;
          pk.u[0] = pk_bf16(v0.x, v0.y);
          pk.u[1] = pk_bf16(v0.z, v0.w);
          pk.u[2] = pk_bf16(v1.x, v1.y);
          pk.u[3] = pk_bf16(v1.z, v1.w);
          afrag[kt] = pk.v;
        }
      }
      __syncthreads();   // drains B DMA (vmcnt) + A loads

#pragma unroll
      for (int kt = 0; kt < 4; ++kt) {
        int ch = kt * 4 + quad;
#pragma unroll
        for (int t = 0; t < NT; ++t) {
          int brow = t * 16 + m16;
          bf16x8 b = *(const bf16x8*)&Bs[brow * 128 + ((ch + brow) & 15) * 8];
          acc[t] = __builtin_amdgcn_mfma_f32_16x16x32_bf16(
              afrag[kt], b, acc[t], 0, 0, 0);
        }
      }
    }
    STORE(acc, row0);
  }
}

extern "C" void kernel_launch(void* const* d_in, const int* in_sizes, int n_in,
                              void* d_out, int out_size, void* d_ws, size_t ws_size,
                              hipStream_t stream) {
  const float* x     = (const float*)d_in[0];
  const int*   ei    = (const int*)d_in[1];
  const float* w_in  = (const float*)d_in[2];
  const float* b_in  = (const float*)d_in[3];
  const float* w_l1  = (const float*)d_in[4];
  const float* b_l1  = (const float*)d_in[5];
  const float* w_r1  = (const float*)d_in[6];
  const float* g1    = (const float*)d_in[7];
  const float* be1   = (const float*)d_in[8];
  const float* w_l2  = (const float*)d_in[9];
  const float* b_l2  = (const float*)d_in[10];
  const float* w_r2  = (const float*)d_in[11];
  const float* g2    = (const float*)d_in[12];
  const float* be2   = (const float*)d_in[13];
  const float* w_out = (const float*)d_in[14];
  const float* b_out = (const float*)d_in[15];
  float* out = (float*)d_out;

  int N = in_sizes[0] / DIN;
  int E = in_sizes[1] / 2;
  const int* src = ei;       // edge_index[0]
  const int* dst = ei + E;   // edge_index[1]
  int nbkt = (N + BKT_NODES - 1) / BKT_NODES;   // 782

  char* ws = (char*)d_ws;
  size_t off = 0;
  auto alloc = [&](size_t bytes) -> char* {
    char* p = ws + off;
    off += (bytes + 255) & ~(size_t)255;
    return p;
  };
  unsigned short* buf0 = (unsigned short*)alloc((size_t)N * H * 2);  // h0 -> mean2
  unsigned short* buf1 = (unsigned short*)alloc((size_t)N * H * 2);  // mean1 -> h2
  unsigned short* buf2 = (unsigned short*)alloc((size_t)N * H * 2);  // h1
  int* bcur        = (int*)alloc((size_t)nbkt * 4);
  unsigned* bedges = (unsigned*)alloc((size_t)nbkt * BKT_CAP * 4);
  int* csr         = (int*)alloc((size_t)nbkt * CSR_CAP * 4);
  int2* rowdeg     = (int2*)alloc((size_t)N * 8);
  unsigned short* t_in  = (unsigned short*)alloc(32768 * 2);
  unsigned short* t_l1  = (unsigned short*)alloc(16384 * 2);
  unsigned short* t_r1  = (unsigned short*)alloc(16384 * 2);
  unsigned short* t_l2  = (unsigned short*)alloc(16384 * 2);
  unsigned short* t_r2  = (unsigned short*)alloc(16384 * 2);
  unsigned short* t_out = (unsigned short*)alloc(8192 * 2);
  (void)ws_size;

  // ---- CSR build: bucket -> in-LDS counting sort (16B-aligned rows) ----
  hipMemsetAsync(bcur, 0, (size_t)nbkt * 4, stream);
  bucket_fill<<<(E + FILL_EPB - 1) / FILL_EPB, FILL_TPB, 0, stream>>>(
      src, dst, bcur, bedges, nbkt, E);
  bucket_sort<<<nbkt, 256, 0, stream>>>(bcur, bedges, csr, rowdeg, N);
  prep_w<<<(106496 + 255) / 256, 256, 0, stream>>>(
      w_in, w_l1, w_r1, w_l2, w_r2, w_out, t_in, t_l1, t_r1, t_l2, t_r2, t_out);

  int gblocks  = (N + 63) / 64;    // 1563 (64-row blocks)
  int gblocks2 = (N + 127) / 128;  // 782  (128-row merged blocks)
  int ablocks  = (N + 15) / 16;    // 6250 (agg: 4 nodes/wave, 4 waves/block)

  // h0 = relu(x @ w_in + b_in)       [fp32 A, K=256 via 2 phases; v4b path]
  gemm_mfma<2, 128, 256, 256, 128, EPI_RELU, true, false, false>
      <<<gblocks, 256, 0, stream>>>(
      x, x, t_in, t_in, b_in, nullptr, nullptr, buf0, N);
  // mean1
  agg_kernel<<<ablocks, 256, 0, stream>>>((const unsigned*)buf0, rowdeg,
                                          csr, (unsigned*)buf1, N);
  // h1 = relu(bn(mean1@w_l1 + h0@w_r1 + b_l1))   [MERGED, 2 row-tiles]
  gemm_mfma<2, 0, 128, 128, 128, EPI_BN, false, false, true>
      <<<gblocks2, 256, 0, stream>>>(
      buf1, buf0, t_l1, t_r1, b_l1, g1, be1, buf2, N);
  // mean2
  agg_kernel<<<ablocks, 256, 0, stream>>>((const unsigned*)buf2, rowdeg,
                                          csr, (unsigned*)buf0, N);
  // h2 = relu(bn(mean2@w_l2 + h1@w_r2 + b_l2))   [MERGED, 2 row-tiles]
  gemm_mfma<2, 0, 128, 128, 128, EPI_BN, false, false, true>
      <<<gblocks2, 256, 0, stream>>>(
      buf0, buf2, t_l2, t_r2, b_l2, g2, be2, buf1, N);
  // out = h2 @ w_out + b_out         [single phase; v4b path]
  gemm_mfma<1, 0, 128, 128, 64, EPI_NONE, false, true, false>
      <<<gblocks, 256, 0, stream>>>(
      buf1, buf1, t_out, t_out, b_out, nullptr, nullptr, out, N);
}